// Round 1
// baseline (10100.549 us; speedup 1.0000x reference)
//
#include <hip/hip_runtime.h>
#include <math.h>

#define NN 4000
#define TG 32
#define TT 16
#define FF 256
#define HH 384
#define H3 1152
#define GCOLS 1536
#define KCAT 640
#define EE 64000
#define D4 512

static __device__ __forceinline__ float sigf(float x) { return 1.0f / (1.0f + expf(-x)); }

// ---------------- combined weight prep ----------------
// z=0: GRU  Wg[1536][640]: rows 0..767 [wi_rz | wh_rz], 768..1151 [wi_n | 0], 1152..1535 [0 | wh_n]
// z=1,2: tree Wt[z-1][1536][640]: rows 0..1151 [ioux | iouh], 1152..1535 [fx | fh]
__global__ __launch_bounds__(256) void prep_weights_kernel(
    const float* __restrict__ gwi, const float* __restrict__ gwh,
    const float* __restrict__ gbi, const float* __restrict__ gbh,
    const float* __restrict__ x1w, const float* __restrict__ x1b,
    const float* __restrict__ h1w, const float* __restrict__ h1b,
    const float* __restrict__ fx1w, const float* __restrict__ fx1b,
    const float* __restrict__ fh1w, const float* __restrict__ fh1b,
    const float* __restrict__ x2w, const float* __restrict__ x2b,
    const float* __restrict__ h2w, const float* __restrict__ h2b,
    const float* __restrict__ fx2w, const float* __restrict__ fx2b,
    const float* __restrict__ fh2w, const float* __restrict__ fh2b,
    float* __restrict__ Wg, float* __restrict__ bg,
    float* __restrict__ Wt, float* __restrict__ bt)
{
    int z = blockIdx.z;
    int idx = blockIdx.x * 256 + threadIdx.x;   // < 1536*640
    int r = idx / KCAT, k = idx - r * KCAT;
    if (z == 0) {
        float v;
        if (r < 768)      v = (k < FF) ? gwi[r*FF + k] : gwh[r*HH + (k-FF)];
        else if (r < H3)  v = (k < FF) ? gwi[r*FF + k] : 0.0f;
        else              v = (k < FF) ? 0.0f : gwh[(r-HH)*HH + (k-FF)];
        Wg[idx] = v;
        if (idx < GCOLS) {
            float b;
            if (idx < 768)     b = gbi[idx] + gbh[idx];
            else if (idx < H3) b = gbi[idx];
            else               b = gbh[idx - HH];
            bg[idx] = b;
        }
    } else {
        const float* xw  = (z==1)? x1w  : x2w;   const float* xb  = (z==1)? x1b  : x2b;
        const float* hw  = (z==1)? h1w  : h2w;   const float* hb  = (z==1)? h1b  : h2b;
        const float* fxw = (z==1)? fx1w : fx2w;  const float* fxb = (z==1)? fx1b : fx2b;
        const float* fhw = (z==1)? fh1w : fh2w;  const float* fhb = (z==1)? fh1b : fh2b;
        float* W = Wt + (size_t)(z-1)*GCOLS*KCAT;
        float* b = bt + (size_t)(z-1)*GCOLS;
        float v;
        if (r < H3) v = (k < FF) ? xw[r*FF + k] : hw[r*HH + (k-FF)];
        else        v = (k < FF) ? fxw[(r-H3)*FF + k] : fhw[(r-H3)*HH + (k-FF)];
        W[idx] = v;
        if (idx < GCOLS)
            b[idx] = (idx < H3) ? (xb[idx] + hb[idx]) : (fxb[idx-H3] + fhb[idx-H3]);
    }
}

// ---------------- generic fp32 GEMM:  C = [X | H] @ W^T (+ bias) ----------------
// A row = concat(X[row] (k1 cols, row stride xStride, col offset xBase), Hm[row] (k2 cols))
// W row-major [NC][K].  z selects (X0/X1, H block, W block, C block) for batched trees.
#define BM 128
#define BN 128
#define BK 32

__global__ __launch_bounds__(256) void gemm_kernel(
    const float* __restrict__ X0, const float* __restrict__ X1,
    int xStride, int xBase, int k1,
    const float* __restrict__ Hb, int k2,
    const float* __restrict__ Wb, const float* __restrict__ biasb, int hasBias,
    float* __restrict__ Cb, int ldC, int M, int NC)
{
    const int z = blockIdx.z;
    const float* X  = (z == 0) ? X0 : X1;
    const float* Hm = Hb + (size_t)z * (size_t)M * (size_t)k2;
    const int K = k1 + k2;
    const float* W = Wb + (size_t)z * (size_t)NC * (size_t)K;
    float* C = Cb + (size_t)z * (size_t)M * (size_t)ldC;

    __shared__ __align__(16) float As[BK][BM+4];
    __shared__ __align__(16) float Ws[BK][BN+4];

    const int tid  = threadIdx.x;
    const int w    = tid >> 6;
    const int lane = tid & 63;
    const int tx = ((w & 1) << 3) | (lane & 7);    // 0..15
    const int ty = ((w >> 1) << 3) | (lane >> 3);  // 0..15
    const int rowBase = blockIdx.y * BM;
    const int colBase = blockIdx.x * BN;

    float acc[8][8];
    #pragma unroll
    for (int i = 0; i < 8; ++i)
        #pragma unroll
        for (int j = 0; j < 8; ++j) acc[i][j] = 0.0f;

    for (int kt = 0; kt < K; kt += BK) {
        // stage A tile (128 rows x 32 k), transposed into As[k][row]
        #pragma unroll
        for (int i = 0; i < 4; ++i) {
            int f  = tid + 256*i;       // 0..1023 float4 slots
            int rr = f >> 3;
            int c4 = f & 7;
            int grow = rowBase + rr;
            int k = kt + c4*4;
            float4 v = make_float4(0.f, 0.f, 0.f, 0.f);
            if (grow < M) {
                if (k < k1) v = *(const float4*)(X  + (size_t)grow*xStride + xBase + k);
                else        v = *(const float4*)(Hm + (size_t)grow*k2 + (k - k1));
            }
            As[c4*4+0][rr] = v.x; As[c4*4+1][rr] = v.y;
            As[c4*4+2][rr] = v.z; As[c4*4+3][rr] = v.w;
        }
        // stage W tile (128 outcols x 32 k), transposed into Ws[k][col]
        #pragma unroll
        for (int i = 0; i < 4; ++i) {
            int f  = tid + 256*i;
            int cc = f >> 3;
            int c4 = f & 7;
            int k = kt + c4*4;
            float4 v = *(const float4*)(W + (size_t)(colBase + cc)*K + k);
            Ws[c4*4+0][cc] = v.x; Ws[c4*4+1][cc] = v.y;
            Ws[c4*4+2][cc] = v.z; Ws[c4*4+3][cc] = v.w;
        }
        __syncthreads();
        #pragma unroll
        for (int kk = 0; kk < BK; ++kk) {
            const float4* pa = (const float4*)&As[kk][ty << 3];
            const float4* pb = (const float4*)&Ws[kk][tx << 3];
            float4 a0 = pa[0], a1 = pa[1];
            float4 b0 = pb[0], b1 = pb[1];
            float a[8] = {a0.x,a0.y,a0.z,a0.w,a1.x,a1.y,a1.z,a1.w};
            float b[8] = {b0.x,b0.y,b0.z,b0.w,b1.x,b1.y,b1.z,b1.w};
            #pragma unroll
            for (int i = 0; i < 8; ++i)
                #pragma unroll
                for (int j = 0; j < 8; ++j)
                    acc[i][j] = fmaf(a[i], b[j], acc[i][j]);
        }
        __syncthreads();
    }

    #pragma unroll
    for (int i = 0; i < 8; ++i) {
        int r = rowBase + (ty << 3) + i;
        if (r >= M) continue;
        float* crow = C + (size_t)r*ldC + colBase + (tx << 3);
        #pragma unroll
        for (int j = 0; j < 8; ++j) {
            float v = acc[i][j];
            if (hasBias) v += biasb[(size_t)z*NC + colBase + (tx << 3) + j];
            crow[j] = v;
        }
    }
}

// ---------------- gates ----------------
__global__ __launch_bounds__(256) void gru_gate_kernel(const float* __restrict__ G, float* __restrict__ h)
{
    int idx = blockIdx.x*256 + threadIdx.x;  // < NN*HH
    int n = idx / HH, j = idx - n*HH;
    const float* g = G + (size_t)n*GCOLS;
    float r  = sigf(g[j]);
    float zz = sigf(g[HH + j]);
    float nn = tanhf(g[2*HH + j] + r * g[3*HH + j]);
    float hv = h[idx];
    h[idx] = (1.0f - zz)*nn + zz*hv;
}

__global__ __launch_bounds__(256) void tree_gate_kernel(const float* __restrict__ G,
                                                        float* __restrict__ h, float* __restrict__ c)
{
    int z = blockIdx.z;
    int idx = blockIdx.x*256 + threadIdx.x;  // < NN*HH
    int n = idx / HH, j = idx - n*HH;
    const float* g = G + ((size_t)z*NN + n)*GCOLS;
    size_t o = (size_t)z*NN*HH + idx;
    float i  = sigf(g[j]);
    float oo = sigf(g[HH + j]);
    float u  = tanhf(g[2*HH + j]);
    float f  = sigf(g[3*HH + j]);
    float cn = i*u + f*c[o];
    c[o] = cn;
    h[o] = oo * tanhf(cn);
}

// ---------------- GCN helpers ----------------
__global__ __launch_bounds__(256) void count_kernel(const int* __restrict__ col, float* __restrict__ deg)
{
    int e = blockIdx.x*256 + threadIdx.x;
    if (e < EE) atomicAdd(&deg[col[e]], 1.0f);
}

__global__ __launch_bounds__(256) void dinv_kernel(const float* __restrict__ deg, float* __restrict__ dinv)
{
    int n = blockIdx.x*256 + threadIdx.x;
    if (n < NN) dinv[n] = rsqrtf(deg[n] + 1.0f);   // +1 self-loop
}

__global__ __launch_bounds__(256) void scatter_kernel(const float* __restrict__ xw,
    const int* __restrict__ row, const int* __restrict__ col,
    const float* __restrict__ dinv, float* __restrict__ agg)
{
    int tid = blockIdx.x*256 + threadIdx.x;  // < EE*128
    int e = tid >> 7;
    int q = tid & 127;
    int r = row[e], c = col[e];
    float nrm = dinv[r]*dinv[c];
    const float4 v = *(const float4*)(xw + (size_t)r*D4 + q*4);
    float* dst = agg + (size_t)c*D4 + q*4;
    atomicAdd(dst+0, v.x*nrm);
    atomicAdd(dst+1, v.y*nrm);
    atomicAdd(dst+2, v.z*nrm);
    atomicAdd(dst+3, v.w*nrm);
}

__global__ __launch_bounds__(256) void combine_kernel(const float* __restrict__ agg,
    const float* __restrict__ xw, const float* __restrict__ dinv,
    const float* __restrict__ b, float* __restrict__ mout, int relu)
{
    int idx = blockIdx.x*256 + threadIdx.x;  // < NN*D4
    int n = idx >> 9, f = idx & 511;
    float v = agg[idx] + xw[idx]*dinv[n]*dinv[n] + b[f];
    if (relu) v = fmaxf(v, 0.0f);
    mout[idx] = v;
}

// ---------------- head: logits + softmax + transpose ----------------
__global__ __launch_bounds__(256) void final_kernel(const float* __restrict__ m,
    const float* __restrict__ w, const float* __restrict__ b, float* __restrict__ out)
{
    int wave = threadIdx.x >> 6;
    int lane = threadIdx.x & 63;
    int n = blockIdx.x*4 + wave;
    const float* row = m + (size_t)n*D4 + lane*8;
    float4 v0 = *(const float4*)(row);
    float4 v1 = *(const float4*)(row + 4);
    const float* w0 = w + lane*8;
    const float* w1 = w + D4 + lane*8;
    float4 u0 = *(const float4*)(w0); float4 u1 = *(const float4*)(w0 + 4);
    float4 t0 = *(const float4*)(w1); float4 t1 = *(const float4*)(w1 + 4);
    float a = v0.x*u0.x + v0.y*u0.y + v0.z*u0.z + v0.w*u0.w
            + v1.x*u1.x + v1.y*u1.y + v1.z*u1.z + v1.w*u1.w;
    float bb = v0.x*t0.x + v0.y*t0.y + v0.z*t0.z + v0.w*t0.w
             + v1.x*t1.x + v1.y*t1.y + v1.z*t1.z + v1.w*t1.w;
    #pragma unroll
    for (int s = 32; s; s >>= 1) { a += __shfl_xor(a, s); bb += __shfl_xor(bb, s); }
    if (lane == 0) {
        float l0 = a + b[0], l1 = bb + b[1];
        float mx = fmaxf(l0, l1);
        float e0 = expf(l0 - mx), e1 = expf(l1 - mx);
        float s = e0 + e1;
        out[n]      = e0 / s;
        out[NN + n] = e1 / s;
    }
}

extern "C" void kernel_launch(void* const* d_in, const int* in_sizes, int n_in,
                              void* d_out, int out_size, void* d_ws, size_t ws_size,
                              hipStream_t stream)
{
    const float* feat1 = (const float*)d_in[0];
    const float* feat2 = (const float*)d_in[1];
    const float* feat3 = (const float*)d_in[2];
    const float* feat4 = (const float*)d_in[3];
    const int*   eidx  = (const int*)d_in[4];
    const float* gwi = (const float*)d_in[5];
    const float* gwh = (const float*)d_in[6];
    const float* gbi = (const float*)d_in[7];
    const float* gbh = (const float*)d_in[8];
    const float* r1w = (const float*)d_in[25]; const float* r1b = (const float*)d_in[26];
    const float* r2w = (const float*)d_in[27]; const float* r2b = (const float*)d_in[28];
    const float* r3w = (const float*)d_in[29]; const float* r3b = (const float*)d_in[30];
    const float* r4w = (const float*)d_in[31]; const float* r4b = (const float*)d_in[32];
    const float* g0w = (const float*)d_in[33]; const float* g0b = (const float*)d_in[34];
    const float* g1w = (const float*)d_in[35]; const float* g1b = (const float*)d_in[36];
    const float* r7w = (const float*)d_in[37]; const float* r7b = (const float*)d_in[38];

    float* ws = (float*)d_ws;
    size_t o = 0;
    float* h_gru = ws;      o += (size_t)NN*HH;        // 1.536M
    float* h_t   = ws + o;  o += (size_t)2*NN*HH;      // 3.072M
    float* c_t   = ws + o;  o += (size_t)2*NN*HH;      // 3.072M
    size_t zeroFloats = o;                             // zero h & c every call
    float* G     = ws + o;  o += (size_t)2*NN*GCOLS;   // 12.288M
    float* Wg    = ws + o;  o += (size_t)GCOLS*KCAT;
    float* Wt    = ws + o;  o += (size_t)2*GCOLS*KCAT;
    float* bg    = ws + o;  o += GCOLS;
    float* bt    = ws + o;  o += 2*GCOLS;
    float* mbuf  = ws + o;  o += (size_t)NN*D4;
    float* xwb   = ws + o;  o += (size_t)NN*D4;
    float* aggb  = ws + o;  o += (size_t)NN*D4;
    float* deg   = ws + o;  o += NN;
    float* dinv  = ws + o;  o += NN;

    hipMemsetAsync(h_gru, 0, zeroFloats*sizeof(float), stream);
    hipMemsetAsync(deg, 0, NN*sizeof(float), stream);

    prep_weights_kernel<<<dim3(3840,1,3),256,0,stream>>>(gwi,gwh,gbi,gbh,
        (const float*)d_in[9],(const float*)d_in[10],(const float*)d_in[11],(const float*)d_in[12],
        (const float*)d_in[13],(const float*)d_in[14],(const float*)d_in[15],(const float*)d_in[16],
        (const float*)d_in[17],(const float*)d_in[18],(const float*)d_in[19],(const float*)d_in[20],
        (const float*)d_in[21],(const float*)d_in[22],(const float*)d_in[23],(const float*)d_in[24],
        Wg,bg,Wt,bt);

    count_kernel<<<250,256,0,stream>>>(eidx + EE, deg);
    dinv_kernel<<<16,256,0,stream>>>(deg, dinv);

    // ---- GRU: 32 steps, fused [x_t | h] GEMM + gate ----
    for (int t = 0; t < TG; ++t) {
        gemm_kernel<<<dim3(GCOLS/BN, 32, 1),256,0,stream>>>(
            feat1, feat1, TG*FF, t*FF, FF, h_gru, HH, Wg, bg, 1, G, GCOLS, NN, GCOLS);
        gru_gate_kernel<<<6000,256,0,stream>>>(G, h_gru);
    }
    // ---- Trees: 16 steps, both trees batched via gridDim.z=2 ----
    for (int t = 0; t < TT; ++t) {
        gemm_kernel<<<dim3(GCOLS/BN, 32, 2),256,0,stream>>>(
            feat2, feat3, TT*FF, t*FF, FF, h_t, HH, Wt, bt, 1, G, GCOLS, NN, GCOLS);
        tree_gate_kernel<<<dim3(6000,1,2),256,0,stream>>>(G, h_t, c_t);
    }

    // ---- projections into mbuf columns [f1|f2|f3|f4] ----
    gemm_kernel<<<dim3(1,32,1),256,0,stream>>>(h_gru, h_gru, HH, 0, HH, h_gru, 0,
        r1w, r1b, 1, mbuf + 0,   D4, NN, 128);
    gemm_kernel<<<dim3(1,32,1),256,0,stream>>>(h_t, h_t, HH, 0, HH, h_t, 0,
        r2w, r2b, 1, mbuf + 128, D4, NN, 128);
    gemm_kernel<<<dim3(1,32,1),256,0,stream>>>(h_t + (size_t)NN*HH, h_t, HH, 0, HH, h_t, 0,
        r3w, r3b, 1, mbuf + 256, D4, NN, 128);
    gemm_kernel<<<dim3(1,32,1),256,0,stream>>>(feat4, feat4, D4, 0, D4, feat4, 0,
        r4w, r4b, 1, mbuf + 384, D4, NN, 128);

    // ---- GCN layer 0 (relu) ----
    gemm_kernel<<<dim3(4,32,1),256,0,stream>>>(mbuf, mbuf, D4, 0, D4, mbuf, 0,
        g0w, (const float*)0, 0, xwb, D4, NN, D4);
    hipMemsetAsync(aggb, 0, (size_t)NN*D4*sizeof(float), stream);
    scatter_kernel<<<32000,256,0,stream>>>(xwb, eidx, eidx + EE, dinv, aggb);
    combine_kernel<<<8000,256,0,stream>>>(aggb, xwb, dinv, g0b, mbuf, 1);

    // ---- GCN layer 1 ----
    gemm_kernel<<<dim3(4,32,1),256,0,stream>>>(mbuf, mbuf, D4, 0, D4, mbuf, 0,
        g1w, (const float*)0, 0, xwb, D4, NN, D4);
    hipMemsetAsync(aggb, 0, (size_t)NN*D4*sizeof(float), stream);
    scatter_kernel<<<32000,256,0,stream>>>(xwb, eidx, eidx + EE, dinv, aggb);
    combine_kernel<<<8000,256,0,stream>>>(aggb, xwb, dinv, g1b, mbuf, 0);

    final_kernel<<<1000,256,0,stream>>>(mbuf, r7w, r7b, (float*)d_out);
}

// Round 2
// 2449.008 us; speedup vs baseline: 4.1243x; 4.1243x over previous
//
#include <hip/hip_runtime.h>
#include <hip/hip_bf16.h>
#include <math.h>

#define NN 4000
#define TG 32
#define TT 16
#define FF 256
#define HH 384
#define H3 1152
#define GCOLS 1536
#define KCAT 640
#define EE 64000
#define D4 512

typedef __attribute__((ext_vector_type(8))) short short8;
typedef __attribute__((ext_vector_type(4))) float float4v;

static __device__ __forceinline__ float sigf(float x) { return 1.0f / (1.0f + expf(-x)); }

static __device__ __forceinline__ void async_copy16(const void* g, void* l) {
    __builtin_amdgcn_global_load_lds(
        (const __attribute__((address_space(1))) unsigned int*)g,
        (__attribute__((address_space(3))) unsigned int*)l, 16, 0, 0);
}

// ---------------- combined weight prep (bf16 weights, fp32 biases) ----------------
// z=0: GRU  Wg[1536][640]: rows 0..767 [wi_rz | wh_rz], 768..1151 [wi_n | 0], 1152..1535 [0 | wh_n]
// z=1,2: tree Wt[z-1][1536][640]: rows 0..1151 [ioux | iouh], 1152..1535 [fx | fh]
__global__ __launch_bounds__(256) void prep_weights_kernel(
    const float* __restrict__ gwi, const float* __restrict__ gwh,
    const float* __restrict__ gbi, const float* __restrict__ gbh,
    const float* __restrict__ x1w, const float* __restrict__ x1b,
    const float* __restrict__ h1w, const float* __restrict__ h1b,
    const float* __restrict__ fx1w, const float* __restrict__ fx1b,
    const float* __restrict__ fh1w, const float* __restrict__ fh1b,
    const float* __restrict__ x2w, const float* __restrict__ x2b,
    const float* __restrict__ h2w, const float* __restrict__ h2b,
    const float* __restrict__ fx2w, const float* __restrict__ fx2b,
    const float* __restrict__ fh2w, const float* __restrict__ fh2b,
    __hip_bfloat16* __restrict__ Wg, float* __restrict__ bg,
    __hip_bfloat16* __restrict__ Wt, float* __restrict__ bt)
{
    int z = blockIdx.z;
    int idx = blockIdx.x * 256 + threadIdx.x;   // < 1536*640
    int r = idx / KCAT, k = idx - r * KCAT;
    if (z == 0) {
        float v;
        if (r < 768)      v = (k < FF) ? gwi[r*FF + k] : gwh[r*HH + (k-FF)];
        else if (r < H3)  v = (k < FF) ? gwi[r*FF + k] : 0.0f;
        else              v = (k < FF) ? 0.0f : gwh[(r-HH)*HH + (k-FF)];
        Wg[idx] = __float2bfloat16(v);
        if (idx < GCOLS) {
            float b;
            if (idx < 768)     b = gbi[idx] + gbh[idx];
            else if (idx < H3) b = gbi[idx];
            else               b = gbh[idx - HH];
            bg[idx] = b;
        }
    } else {
        const float* xw  = (z==1)? x1w  : x2w;   const float* xb  = (z==1)? x1b  : x2b;
        const float* hw  = (z==1)? h1w  : h2w;   const float* hb  = (z==1)? h1b  : h2b;
        const float* fxw = (z==1)? fx1w : fx2w;  const float* fxb = (z==1)? fx1b : fx2b;
        const float* fhw = (z==1)? fh1w : fh2w;  const float* fhb = (z==1)? fh1b : fh2b;
        __hip_bfloat16* W = Wt + (size_t)(z-1)*GCOLS*KCAT;
        float* b = bt + (size_t)(z-1)*GCOLS;
        float v;
        if (r < H3) v = (k < FF) ? xw[r*FF + k] : hw[r*HH + (k-FF)];
        else        v = (k < FF) ? fxw[(r-H3)*FF + k] : fhw[(r-H3)*HH + (k-FF)];
        W[idx] = __float2bfloat16(v);
        if (idx < GCOLS)
            b[idx] = (idx < H3) ? (xb[idx] + hb[idx]) : (fxb[idx-H3] + fhb[idx-H3]);
    }
}

// ---------------- fp32 -> bf16 copy ----------------
__global__ __launch_bounds__(256) void f2b_kernel(const float* __restrict__ s,
                                                  __hip_bfloat16* __restrict__ d, int n)
{
    int i = blockIdx.x*256 + threadIdx.x;
    if (i < n) d[i] = __float2bfloat16(s[i]);
}

// ---------------- x(t=0) conversion into packed A buffers ----------------
__global__ __launch_bounds__(256) void convert_x0_kernel(const float* __restrict__ f1,
    const float* __restrict__ f2, const float* __restrict__ f3,
    __hip_bfloat16* __restrict__ Abg, __hip_bfloat16* __restrict__ Abt)
{
    int z = blockIdx.z;
    int i = blockIdx.x*256 + threadIdx.x;   // < NN*FF
    if (i >= NN*FF) return;
    int n = i >> 8, f = i & 255;
    if (z == 0) {
        Abg[(size_t)n*KCAT + f] = __float2bfloat16(f1[(size_t)n*TG*FF + f]);
    } else {
        const float* s = (z==1) ? f2 : f3;
        (Abt + (size_t)(z-1)*NN*KCAT)[(size_t)n*KCAT + f] =
            __float2bfloat16(s[(size_t)n*TT*FF + f]);
    }
}

// ---------------- bf16 MFMA GEMM:  C[M][NC] = A[M][K] @ W[NC][K]^T (+bias) ----------------
// m97 structure: 128x128 tile, BK=32, 4 waves (2x2), 16x16x32 MFMA, global_load_lds w=16.
#define BM 128
#define BN 128
#define BKK 32

__global__ __launch_bounds__(256) void gemm_bf16_kernel(
    const __hip_bfloat16* __restrict__ Ab, int lda, size_t zA,
    const __hip_bfloat16* __restrict__ Wb, size_t zW, int K,
    const float* __restrict__ biasb, size_t zBias, int hasBias,
    float* __restrict__ Cb, int ldC, size_t zC, int M,
    __hip_bfloat16* __restrict__ C16)
{
    const int z = blockIdx.z;
    const __hip_bfloat16* A = Ab + zA * z;
    const __hip_bfloat16* W = Wb + zW * z;
    float* C = Cb + zC * z;

    __shared__ __align__(16) __hip_bfloat16 As[BM][BKK];
    __shared__ __align__(16) __hip_bfloat16 Bs[BN][BKK];

    const int tid  = threadIdx.x;
    const int lane = tid & 63;
    const int w    = tid >> 6;
    const int wr = w >> 1, wc = w & 1;
    const int rowBase = blockIdx.y * BM;
    const int colBase = blockIdx.x * BN;

    const int sRow = tid >> 2;          // 0..63 (+64 per issue)
    const int sK   = (tid & 3) * 8;     // element offset in k

    float4v acc[4][4];
    #pragma unroll
    for (int i = 0; i < 4; ++i)
        #pragma unroll
        for (int j = 0; j < 4; ++j)
            acc[i][j] = (float4v){0.f, 0.f, 0.f, 0.f};

    const int rl = lane & 15;
    const int kl = (lane >> 4) * 8;

    for (int kt = 0; kt < K; kt += BKK) {
        #pragma unroll
        for (int i = 0; i < 2; ++i) {
            int r = i*64 + sRow;
            int gr = rowBase + r; if (gr > M-1) gr = M-1;
            async_copy16(A + (size_t)gr*lda + kt + sK, &As[r][sK]);
        }
        #pragma unroll
        for (int i = 0; i < 2; ++i) {
            int r = i*64 + sRow;
            async_copy16(W + (size_t)(colBase + r)*K + kt + sK, &Bs[r][sK]);
        }
        __syncthreads();

        short8 af[4], bfr[4];
        #pragma unroll
        for (int mi = 0; mi < 4; ++mi)
            af[mi] = *(const short8*)&As[wr*64 + mi*16 + rl][kl];
        #pragma unroll
        for (int ni = 0; ni < 4; ++ni)
            bfr[ni] = *(const short8*)&Bs[wc*64 + ni*16 + rl][kl];
        #pragma unroll
        for (int mi = 0; mi < 4; ++mi)
            #pragma unroll
            for (int ni = 0; ni < 4; ++ni)
                acc[mi][ni] = __builtin_amdgcn_mfma_f32_16x16x32_bf16(af[mi], bfr[ni], acc[mi][ni], 0, 0, 0);
        __syncthreads();
    }

    const int rq = (lane >> 4) * 4;
    #pragma unroll
    for (int mi = 0; mi < 4; ++mi) {
        #pragma unroll
        for (int q = 0; q < 4; ++q) {
            int row = rowBase + wr*64 + mi*16 + rq + q;
            if (row >= M) continue;
            #pragma unroll
            for (int ni = 0; ni < 4; ++ni) {
                int col = colBase + wc*64 + ni*16 + rl;
                float v = acc[mi][ni][q];
                if (hasBias) v += biasb[zBias*z + col];
                C[(size_t)row*ldC + col] = v;
                if (C16) C16[(size_t)row*ldC + col] = __float2bfloat16(v);
            }
        }
    }
}

// ---------------- gates (also write bf16 h into packed A-buf + convert next x) ----------------
__global__ __launch_bounds__(256) void gru_gate_kernel(const float* __restrict__ G,
    float* __restrict__ h, __hip_bfloat16* __restrict__ Ab,
    const float* __restrict__ xnext, int xstride)
{
    int idx = blockIdx.x*256 + threadIdx.x;  // < NN*HH
    int n = idx / HH, j = idx - n*HH;
    const float* g = G + (size_t)n*GCOLS;
    float r  = sigf(g[j]);
    float zz = sigf(g[HH + j]);
    float nn = tanhf(g[2*HH + j] + r * g[3*HH + j]);
    float hv = h[idx];
    float hn = (1.0f - zz)*nn + zz*hv;
    h[idx] = hn;
    Ab[(size_t)n*KCAT + FF + j] = __float2bfloat16(hn);
    if (xnext && idx < NN*FF) {
        int n2 = idx >> 8, f = idx & 255;
        Ab[(size_t)n2*KCAT + f] = __float2bfloat16(xnext[(size_t)n2*xstride + f]);
    }
}

__global__ __launch_bounds__(256) void tree_gate_kernel(const float* __restrict__ G,
    float* __restrict__ h, float* __restrict__ c, __hip_bfloat16* __restrict__ Abt,
    const float* __restrict__ x2next, const float* __restrict__ x3next, int xstride)
{
    int z = blockIdx.z;
    int idx = blockIdx.x*256 + threadIdx.x;  // < NN*HH
    int n = idx / HH, j = idx - n*HH;
    const float* g = G + ((size_t)z*NN + n)*GCOLS;
    size_t o = (size_t)z*NN*HH + idx;
    __hip_bfloat16* Ab = Abt + (size_t)z*NN*KCAT;
    float i  = sigf(g[j]);
    float oo = sigf(g[HH + j]);
    float u  = tanhf(g[2*HH + j]);
    float f  = sigf(g[3*HH + j]);
    float cn = i*u + f*c[o];
    c[o] = cn;
    float hn = oo * tanhf(cn);
    h[o] = hn;
    Ab[(size_t)n*KCAT + FF + j] = __float2bfloat16(hn);
    const float* xn = (z == 0) ? x2next : x3next;
    if (xn && idx < NN*FF) {
        int n2 = idx >> 8, f2 = idx & 255;
        Ab[(size_t)n2*KCAT + f2] = __float2bfloat16(xn[(size_t)n2*xstride + f2]);
    }
}

// ---------------- GCN: CSR build + gather ----------------
__global__ __launch_bounds__(256) void count_kernel(const int* __restrict__ col, int* __restrict__ degi)
{
    int e = blockIdx.x*256 + threadIdx.x;
    if (e < EE) atomicAdd(&degi[col[e]], 1);
}

__global__ __launch_bounds__(1024) void scan_kernel(const int* __restrict__ degi,
    int* __restrict__ start, int* __restrict__ cursor, float* __restrict__ dinv)
{
    __shared__ int s[1024];
    int t = threadIdx.x;
    int v[4]; int sum = 0;
    #pragma unroll
    for (int i = 0; i < 4; ++i) {
        int idx = t*4 + i;
        v[i] = (idx < NN) ? degi[idx] : 0;
        sum += v[i];
    }
    s[t] = sum;
    __syncthreads();
    for (int d = 1; d < 1024; d <<= 1) {
        int x = (t >= d) ? s[t-d] : 0;
        __syncthreads();
        s[t] += x;
        __syncthreads();
    }
    int base = s[t] - sum;   // exclusive
    int run = 0;
    #pragma unroll
    for (int i = 0; i < 4; ++i) {
        int idx = t*4 + i;
        if (idx < NN) {
            int st = base + run;
            start[idx] = st;
            cursor[idx] = st;
            dinv[idx] = rsqrtf((float)v[i] + 1.0f);
        }
        run += v[i];
    }
    if (t == 1023) start[NN] = s[1023];
}

__global__ __launch_bounds__(256) void fill_kernel(const int* __restrict__ row,
    const int* __restrict__ col, int* __restrict__ cursor, int* __restrict__ esrc)
{
    int e = blockIdx.x*256 + threadIdx.x;
    if (e < EE) {
        int c = col[e];
        int pos = atomicAdd(&cursor[c], 1);
        esrc[pos] = row[e];
    }
}

// one wave per node; fuses aggregation + self-loop + bias + relu
__global__ __launch_bounds__(256) void gather_kernel(const float* __restrict__ xw,
    const int* __restrict__ esrc, const int* __restrict__ start,
    const float* __restrict__ dinv, const float* __restrict__ bias,
    float* __restrict__ mout, __hip_bfloat16* __restrict__ mout16, int relu)
{
    int wv = threadIdx.x >> 6, lane = threadIdx.x & 63;
    int n = blockIdx.x*4 + wv;
    if (n >= NN) return;
    float a[8] = {0.f,0.f,0.f,0.f,0.f,0.f,0.f,0.f};
    int s0 = start[n], s1 = start[n+1];
    float dn = dinv[n];
    for (int e = s0; e < s1; ++e) {
        int r = esrc[e];
        float nrm = dinv[r]*dn;
        const float4 v0 = *(const float4*)(xw + (size_t)r*D4 + lane*8);
        const float4 v1 = *(const float4*)(xw + (size_t)r*D4 + lane*8 + 4);
        a[0] += v0.x*nrm; a[1] += v0.y*nrm; a[2] += v0.z*nrm; a[3] += v0.w*nrm;
        a[4] += v1.x*nrm; a[5] += v1.y*nrm; a[6] += v1.z*nrm; a[7] += v1.w*nrm;
    }
    const float4 u0 = *(const float4*)(xw + (size_t)n*D4 + lane*8);
    const float4 u1 = *(const float4*)(xw + (size_t)n*D4 + lane*8 + 4);
    float dd = dn*dn;
    float su[8] = {u0.x,u0.y,u0.z,u0.w,u1.x,u1.y,u1.z,u1.w};
    #pragma unroll
    for (int i = 0; i < 8; ++i) {
        float vv = a[i] + su[i]*dd + bias[lane*8 + i];
        if (relu) vv = fmaxf(vv, 0.0f);
        mout[(size_t)n*D4 + lane*8 + i] = vv;
        if (mout16) mout16[(size_t)n*D4 + lane*8 + i] = __float2bfloat16(vv);
    }
}

// ---------------- head: logits + softmax + transpose ----------------
__global__ __launch_bounds__(256) void final_kernel(const float* __restrict__ m,
    const float* __restrict__ w, const float* __restrict__ b, float* __restrict__ out)
{
    int wave = threadIdx.x >> 6;
    int lane = threadIdx.x & 63;
    int n = blockIdx.x*4 + wave;
    const float* row = m + (size_t)n*D4 + lane*8;
    float4 v0 = *(const float4*)(row);
    float4 v1 = *(const float4*)(row + 4);
    const float* w0 = w + lane*8;
    const float* w1 = w + D4 + lane*8;
    float4 u0 = *(const float4*)(w0); float4 u1 = *(const float4*)(w0 + 4);
    float4 t0 = *(const float4*)(w1); float4 t1 = *(const float4*)(w1 + 4);
    float a = v0.x*u0.x + v0.y*u0.y + v0.z*u0.z + v0.w*u0.w
            + v1.x*u1.x + v1.y*u1.y + v1.z*u1.z + v1.w*u1.w;
    float bb = v0.x*t0.x + v0.y*t0.y + v0.z*t0.z + v0.w*t0.w
             + v1.x*t1.x + v1.y*t1.y + v1.z*t1.z + v1.w*t1.w;
    #pragma unroll
    for (int s = 32; s; s >>= 1) { a += __shfl_xor(a, s); bb += __shfl_xor(bb, s); }
    if (lane == 0) {
        float l0 = a + b[0], l1 = bb + b[1];
        float mx = fmaxf(l0, l1);
        float e0 = expf(l0 - mx), e1 = expf(l1 - mx);
        float s = e0 + e1;
        out[n]      = e0 / s;
        out[NN + n] = e1 / s;
    }
}

extern "C" void kernel_launch(void* const* d_in, const int* in_sizes, int n_in,
                              void* d_out, int out_size, void* d_ws, size_t ws_size,
                              hipStream_t stream)
{
    const float* feat1 = (const float*)d_in[0];
    const float* feat2 = (const float*)d_in[1];
    const float* feat3 = (const float*)d_in[2];
    const float* feat4 = (const float*)d_in[3];
    const int*   eidx  = (const int*)d_in[4];
    const float* r1w = (const float*)d_in[25]; const float* r1b = (const float*)d_in[26];
    const float* r2w = (const float*)d_in[27]; const float* r2b = (const float*)d_in[28];
    const float* r3w = (const float*)d_in[29]; const float* r3b = (const float*)d_in[30];
    const float* r4w = (const float*)d_in[31]; const float* r4b = (const float*)d_in[32];
    const float* g0w = (const float*)d_in[33]; const float* g0b = (const float*)d_in[34];
    const float* g1w = (const float*)d_in[35]; const float* g1b = (const float*)d_in[36];
    const float* r7w = (const float*)d_in[37]; const float* r7b = (const float*)d_in[38];

    float* ws = (float*)d_ws;
    size_t o = 0;
    auto alloc = [&](size_t nfl) { float* p = ws + o; o += (nfl + 3) & ~(size_t)3; return p; };

    float* h_gru = alloc((size_t)NN*HH);
    float* h_t   = alloc((size_t)2*NN*HH);
    float* c_t   = alloc((size_t)2*NN*HH);
    size_t zeroFloats = o;                                  // h & c zeroed every call
    float* G     = alloc((size_t)2*NN*GCOLS);
    float* mbuf  = alloc((size_t)NN*D4);
    float* xwb   = alloc((size_t)NN*D4);
    float* bg    = alloc(GCOLS);
    float* bt    = alloc(2*GCOLS);
    float* dinv  = alloc(NN);
    __hip_bfloat16* Abg   = (__hip_bfloat16*)alloc((size_t)NN*KCAT/2);
    __hip_bfloat16* Abt   = (__hip_bfloat16*)alloc((size_t)2*NN*KCAT/2);
    __hip_bfloat16* Wg16  = (__hip_bfloat16*)alloc((size_t)GCOLS*KCAT/2);
    __hip_bfloat16* Wt16  = (__hip_bfloat16*)alloc((size_t)2*GCOLS*KCAT/2);
    __hip_bfloat16* f4b   = (__hip_bfloat16*)alloc((size_t)NN*D4/2);
    __hip_bfloat16* mbf16 = (__hip_bfloat16*)alloc((size_t)NN*D4/2);
    __hip_bfloat16* r1w16 = (__hip_bfloat16*)alloc(128*HH/2);
    __hip_bfloat16* r2w16 = (__hip_bfloat16*)alloc(128*HH/2);
    __hip_bfloat16* r3w16 = (__hip_bfloat16*)alloc(128*HH/2);
    __hip_bfloat16* r4w16 = (__hip_bfloat16*)alloc(128*D4/2);
    __hip_bfloat16* g0w16 = (__hip_bfloat16*)alloc((size_t)D4*D4/2);
    __hip_bfloat16* g1w16 = (__hip_bfloat16*)alloc((size_t)D4*D4/2);
    int* degi   = (int*)alloc(NN);
    int* start  = (int*)alloc(NN + 4);
    int* cursor = (int*)alloc(NN);
    int* esrc   = (int*)alloc(EE);

    hipMemsetAsync(h_gru, 0, zeroFloats*sizeof(float), stream);
    hipMemsetAsync(degi, 0, NN*sizeof(int), stream);
    hipMemsetAsync(Abg, 0, (size_t)NN*KCAT*2, stream);
    hipMemsetAsync(Abt, 0, (size_t)2*NN*KCAT*2, stream);

    prep_weights_kernel<<<dim3(3840,1,3),256,0,stream>>>(
        (const float*)d_in[5],(const float*)d_in[6],(const float*)d_in[7],(const float*)d_in[8],
        (const float*)d_in[9],(const float*)d_in[10],(const float*)d_in[11],(const float*)d_in[12],
        (const float*)d_in[13],(const float*)d_in[14],(const float*)d_in[15],(const float*)d_in[16],
        (const float*)d_in[17],(const float*)d_in[18],(const float*)d_in[19],(const float*)d_in[20],
        (const float*)d_in[21],(const float*)d_in[22],(const float*)d_in[23],(const float*)d_in[24],
        Wg16, bg, Wt16, bt);

    f2b_kernel<<<8000,256,0,stream>>>(feat4, f4b, NN*D4);
    f2b_kernel<<<192,256,0,stream>>>(r1w, r1w16, 128*HH);
    f2b_kernel<<<192,256,0,stream>>>(r2w, r2w16, 128*HH);
    f2b_kernel<<<192,256,0,stream>>>(r3w, r3w16, 128*HH);
    f2b_kernel<<<256,256,0,stream>>>(r4w, r4w16, 128*D4);
    f2b_kernel<<<1024,256,0,stream>>>(g0w, g0w16, D4*D4);
    f2b_kernel<<<1024,256,0,stream>>>(g1w, g1w16, D4*D4);
    convert_x0_kernel<<<dim3(4000,1,3),256,0,stream>>>(feat1, feat2, feat3, Abg, Abt);

    count_kernel<<<250,256,0,stream>>>(eidx + EE, degi);
    scan_kernel<<<1,1024,0,stream>>>(degi, start, cursor, dinv);
    fill_kernel<<<250,256,0,stream>>>(eidx, eidx + EE, cursor, esrc);

    // ---- GRU: 32 steps ----
    for (int t = 0; t < TG; ++t) {
        gemm_bf16_kernel<<<dim3(GCOLS/BN, 32, 1),256,0,stream>>>(
            Abg, KCAT, 0, Wg16, 0, KCAT, bg, 0, 1, G, GCOLS, 0, NN, (__hip_bfloat16*)0);
        gru_gate_kernel<<<6000,256,0,stream>>>(G, h_gru, Abg,
            (t < TG-1) ? feat1 + (size_t)(t+1)*FF : (const float*)0, TG*FF);
    }
    // ---- Trees: 16 steps, batched z=2 ----
    for (int t = 0; t < TT; ++t) {
        gemm_bf16_kernel<<<dim3(GCOLS/BN, 32, 2),256,0,stream>>>(
            Abt, KCAT, (size_t)NN*KCAT, Wt16, (size_t)GCOLS*KCAT, KCAT, bt, GCOLS, 1,
            G, GCOLS, (size_t)NN*GCOLS, NN, (__hip_bfloat16*)0);
        tree_gate_kernel<<<dim3(6000,1,2),256,0,stream>>>(G, h_t, c_t, Abt,
            (t < TT-1) ? feat2 + (size_t)(t+1)*FF : (const float*)0,
            (t < TT-1) ? feat3 + (size_t)(t+1)*FF : (const float*)0, TT*FF);
    }

    // ---- projections into mbuf columns [f1|f2|f3|f4] (fp32 + bf16 mirror) ----
    gemm_bf16_kernel<<<dim3(1,32,1),256,0,stream>>>(Abg + FF, KCAT, 0, r1w16, 0, HH,
        r1b, 0, 1, mbuf + 0, D4, 0, NN, mbf16 + 0);
    gemm_bf16_kernel<<<dim3(1,32,1),256,0,stream>>>(Abt + FF, KCAT, 0, r2w16, 0, HH,
        r2b, 0, 1, mbuf + 128, D4, 0, NN, mbf16 + 128);
    gemm_bf16_kernel<<<dim3(1,32,1),256,0,stream>>>(Abt + (size_t)NN*KCAT + FF, KCAT, 0, r3w16, 0, HH,
        r3b, 0, 1, mbuf + 256, D4, 0, NN, mbf16 + 256);
    gemm_bf16_kernel<<<dim3(1,32,1),256,0,stream>>>(f4b, D4, 0, r4w16, 0, D4,
        r4b, 0, 1, mbuf + 384, D4, 0, NN, mbf16 + 384);

    // ---- GCN layer 0 (relu) ----
    gemm_bf16_kernel<<<dim3(4,32,1),256,0,stream>>>(mbf16, D4, 0, g0w16, 0, D4,
        (const float*)0, 0, 0, xwb, D4, 0, NN, (__hip_bfloat16*)0);
    gather_kernel<<<1000,256,0,stream>>>(xwb, esrc, start, dinv, g0b, mbuf, mbf16, 1);

    // ---- GCN layer 1 ----
    gemm_bf16_kernel<<<dim3(4,32,1),256,0,stream>>>(mbf16, D4, 0, g1w16, 0, D4,
        (const float*)0, 0, 0, xwb, D4, 0, NN, (__hip_bfloat16*)0);
    gather_kernel<<<1000,256,0,stream>>>(xwb, esrc, start, dinv, g1b, mbuf, (__hip_bfloat16*)0, 0);

    final_kernel<<<1000,256,0,stream>>>(mbuf, r7w, r7b, (float*)d_out);
}

// Round 3
// 1705.068 us; speedup vs baseline: 5.9238x; 1.4363x over previous
//
#include <hip/hip_runtime.h>
#include <hip/hip_bf16.h>
#include <math.h>

#define NN 4000
#define TG 32
#define TT 16
#define FF 256
#define HH 384
#define GCOLS 1536
#define KCAT 640
#define EE 64000
#define D4 512

typedef __attribute__((ext_vector_type(8))) short short8;
typedef __attribute__((ext_vector_type(4))) float float4v;

static __device__ __forceinline__ float fsig(float x)  { return 1.0f / (1.0f + __expf(-x)); }
static __device__ __forceinline__ float ftanh(float x) { return 2.0f / (1.0f + __expf(-2.0f*x)) - 1.0f; }

static __device__ __forceinline__ void async_copy16(const void* g, void* l) {
    __builtin_amdgcn_global_load_lds(
        (const __attribute__((address_space(1))) unsigned int*)g,
        (__attribute__((address_space(3))) unsigned int*)l, 16, 0, 0);
}

// ---------------- packed weight prep ----------------
// Column order: c = bx*128 + wc*64 + g*16 + rl ; unit j = bx*32 + wc*16 + rl ; gate g.
// GRU gates: 0=r, 1=z, 2=inn (x-only), 3=hn (h-only). Tree gates: 0=i, 1=o, 2=u, 3=f.
__global__ __launch_bounds__(256) void prep_w_kernel(
    const float* __restrict__ gwi, const float* __restrict__ gwh,
    const float* __restrict__ gbi, const float* __restrict__ gbh,
    const float* __restrict__ x1w, const float* __restrict__ x1b,
    const float* __restrict__ h1w, const float* __restrict__ h1b,
    const float* __restrict__ fx1w, const float* __restrict__ fx1b,
    const float* __restrict__ fh1w, const float* __restrict__ fh1b,
    const float* __restrict__ x2w, const float* __restrict__ x2b,
    const float* __restrict__ h2w, const float* __restrict__ h2b,
    const float* __restrict__ fx2w, const float* __restrict__ fx2b,
    const float* __restrict__ fh2w, const float* __restrict__ fh2b,
    __hip_bfloat16* __restrict__ Wp, float* __restrict__ bp)
{
    int z = blockIdx.z;
    int idx = blockIdx.x * 256 + threadIdx.x;      // < GCOLS*KCAT
    int c = idx / KCAT, k = idx - c * KCAT;
    int bx = c >> 7, wc = (c >> 6) & 1, g = (c >> 4) & 3, rl = c & 15;
    int j = bx*32 + wc*16 + rl;
    float v = 0.0f, bv = 0.0f;
    if (z == 0) {
        if (g <= 1) {
            int row = g*HH + j;
            v = (k < FF) ? gwi[row*FF + k] : gwh[row*HH + (k-FF)];
            bv = gbi[row] + gbh[row];
        } else if (g == 2) {
            int row = 2*HH + j;
            v = (k < FF) ? gwi[row*FF + k] : 0.0f;
            bv = gbi[row];
        } else {
            int row = 2*HH + j;
            v = (k < FF) ? 0.0f : gwh[row*HH + (k-FF)];
            bv = gbh[row];
        }
    } else {
        const float* xw  = (z==1)? x1w  : x2w;   const float* xb  = (z==1)? x1b  : x2b;
        const float* hw  = (z==1)? h1w  : h2w;   const float* hb_ = (z==1)? h1b  : h2b;
        const float* fxw = (z==1)? fx1w : fx2w;  const float* fxb = (z==1)? fx1b : fx2b;
        const float* fhw = (z==1)? fh1w : fh2w;  const float* fhb = (z==1)? fh1b : fh2b;
        if (g < 3) {
            int row = g*HH + j;
            v = (k < FF) ? xw[row*FF + k] : hw[row*HH + (k-FF)];
            bv = xb[row] + hb_[row];
        } else {
            v = (k < FF) ? fxw[j*FF + k] : fhw[j*HH + (k-FF)];
            bv = fxb[j] + fhb[j];
        }
    }
    Wp[(size_t)z*GCOLS*KCAT + idx] = __float2bfloat16(v);
    if (k == 0) bp[z*GCOLS + c] = bv;
}

// ---------------- fp32 -> bf16 copy ----------------
__global__ __launch_bounds__(256) void f2b_kernel(const float* __restrict__ s,
                                                  __hip_bfloat16* __restrict__ d, int n)
{
    int i = blockIdx.x*256 + threadIdx.x;
    if (i < n) d[i] = __float2bfloat16(s[i]);
}

// ---------------- transpose feats to bf16 [t][n][256] ----------------
__global__ __launch_bounds__(256) void tpose_kernel(const float* __restrict__ f1,
    const float* __restrict__ f2, const float* __restrict__ f3,
    __hip_bfloat16* __restrict__ xg, __hip_bfloat16* __restrict__ xt)
{
    int zz = blockIdx.z;
    int gid = blockIdx.x*256 + threadIdx.x;
    int T = (zz == 0) ? TG : TT;
    int rows = NN * T;
    int rowid = gid >> 6;
    if (rowid >= rows) return;
    int f = (gid & 63) * 4;
    int n = rowid / T, t = rowid - n*T;
    const float* src = (zz==0)? f1 : (zz==1)? f2 : f3;
    float4 v = *(const float4*)(src + (size_t)rowid*FF + f);
    __hip_bfloat16* dst = (zz==0)? xg : (xt + (size_t)(zz-1)*TT*NN*FF);
    __hip_bfloat16 b4[4] = {__float2bfloat16(v.x), __float2bfloat16(v.y),
                            __float2bfloat16(v.z), __float2bfloat16(v.w)};
    *(ushort4*)(dst + ((size_t)t*NN + n)*FF + f) = *(const ushort4*)b4;
}

// ---------------- GEMM + fused gates ----------------
// MODE 0: plain  C = A @ W^T (+bias), fp32 out + optional bf16 mirror
// MODE 1: GRU    gates fused; Sin/Sout = fp32 h ping-pong; Hout = bf16 h
// MODE 2: tree   gates fused; Sin/Sout = fp32 c ping-pong; Hout = bf16 h
#define BM 128
#define BN 128
#define BKK 32

template<int MODE>
__global__ __launch_bounds__(256) void gemm_k(
    const __hip_bfloat16* __restrict__ Xb, size_t zX, int ldx, int k1,
    const __hip_bfloat16* __restrict__ Hin, size_t zH,
    const __hip_bfloat16* __restrict__ Wb, size_t zW, int K,
    const float* __restrict__ bp, size_t zB, int hasBias,
    const float* __restrict__ Sin, size_t zS,
    float* __restrict__ Sout, size_t zSo,
    __hip_bfloat16* __restrict__ Hout, size_t zHo,
    int ldC, int M)
{
    const int z = blockIdx.z;
    const __hip_bfloat16* X  = Xb + zX*z;
    const __hip_bfloat16* Hi = (MODE != 0) ? (Hin + zH*z) : nullptr;
    const __hip_bfloat16* W  = Wb + zW*z;

    __shared__ __align__(16) __hip_bfloat16 As[BM][BKK];
    __shared__ __align__(16) __hip_bfloat16 Bs[BN][BKK];

    const int tid  = threadIdx.x;
    const int lane = tid & 63;
    const int w    = tid >> 6;
    const int wr = w >> 1, wc = w & 1;
    const int rowBase = blockIdx.y * BM;
    const int colBase = blockIdx.x * BN;
    const int sRow = tid >> 2;
    const int sK   = (tid & 3) * 8;

    float4v acc[4][4];
    #pragma unroll
    for (int i = 0; i < 4; ++i)
        #pragma unroll
        for (int j = 0; j < 4; ++j)
            acc[i][j] = (float4v){0.f, 0.f, 0.f, 0.f};

    const int rl = lane & 15;
    const int kl = (lane >> 4) * 8;

    for (int kt = 0; kt < K; kt += BKK) {
        const int kk = kt + sK;
        #pragma unroll
        for (int i = 0; i < 2; ++i) {
            int r = i*64 + sRow;
            int gr = rowBase + r; if (gr > M-1) gr = M-1;
            const __hip_bfloat16* src;
            if (MODE == 0 || kk < k1) src = X  + (size_t)gr*ldx + kk;
            else                      src = Hi + (size_t)gr*HH + (kk - k1);
            async_copy16(src, &As[r][sK]);
        }
        #pragma unroll
        for (int i = 0; i < 2; ++i) {
            int r = i*64 + sRow;
            async_copy16(W + (size_t)(colBase + r)*K + kk, &Bs[r][sK]);
        }
        __syncthreads();

        short8 af[4], bfr[4];
        #pragma unroll
        for (int mi = 0; mi < 4; ++mi)
            af[mi] = *(const short8*)&As[wr*64 + mi*16 + rl][kl];
        #pragma unroll
        for (int ni = 0; ni < 4; ++ni)
            bfr[ni] = *(const short8*)&Bs[wc*64 + ni*16 + rl][kl];
        #pragma unroll
        for (int mi = 0; mi < 4; ++mi)
            #pragma unroll
            for (int ni = 0; ni < 4; ++ni)
                acc[mi][ni] = __builtin_amdgcn_mfma_f32_16x16x32_bf16(af[mi], bfr[ni], acc[mi][ni], 0, 0, 0);
        __syncthreads();
    }

    const int rq = (lane >> 4) * 4;

    if (MODE == 0) {
        float* C = Sout + zSo*z;
        __hip_bfloat16* C16 = Hout ? (Hout + zHo*z) : nullptr;
        #pragma unroll
        for (int mi = 0; mi < 4; ++mi) {
            #pragma unroll
            for (int q = 0; q < 4; ++q) {
                int row = rowBase + wr*64 + mi*16 + rq + q;
                if (row >= M) continue;
                #pragma unroll
                for (int ni = 0; ni < 4; ++ni) {
                    int col = colBase + wc*64 + ni*16 + rl;
                    float v = acc[mi][ni][q];
                    if (hasBias) v += bp[zB*z + col];
                    C[(size_t)row*ldC + col] = v;
                    if (C16) C16[(size_t)row*ldC + col] = __float2bfloat16(v);
                }
            }
        }
    } else {
        const int j = (colBase >> 2) + wc*16 + rl;
        const int cb = colBase + wc*64 + rl;
        float b0 = bp[zB*z + cb + 0];
        float b1 = bp[zB*z + cb + 16];
        float b2 = bp[zB*z + cb + 32];
        float b3 = bp[zB*z + cb + 48];
        const float* Si = Sin + zS*z;
        float* So = Sout + zSo*z;
        __hip_bfloat16* Ho = Hout + zHo*z;
        #pragma unroll
        for (int mi = 0; mi < 4; ++mi) {
            #pragma unroll
            for (int q = 0; q < 4; ++q) {
                int row = rowBase + wr*64 + mi*16 + rq + q;
                if (row >= M) continue;
                float g0 = acc[mi][0][q] + b0;
                float g1 = acc[mi][1][q] + b1;
                float g2 = acc[mi][2][q] + b2;
                float g3 = acc[mi][3][q] + b3;
                size_t off = (size_t)row*HH + j;
                if (MODE == 1) {
                    float r  = fsig(g0), zz = fsig(g1);
                    float n  = ftanh(g2 + r*g3);
                    float hp = Si[off];
                    float hn = (1.0f - zz)*n + zz*hp;
                    So[off] = hn;
                    Ho[off] = __float2bfloat16(hn);
                } else {
                    float cp = Si[off];
                    float cn = fsig(g0)*ftanh(g2) + fsig(g3)*cp;
                    So[off] = cn;
                    float hn = fsig(g1)*ftanh(cn);
                    Ho[off] = __float2bfloat16(hn);
                }
            }
        }
    }
}

// ---------------- GCN: CSR build + gather ----------------
__global__ __launch_bounds__(256) void count_kernel(const int* __restrict__ col, int* __restrict__ degi)
{
    int e = blockIdx.x*256 + threadIdx.x;
    if (e < EE) atomicAdd(&degi[col[e]], 1);
}

__global__ __launch_bounds__(1024) void scan_kernel(const int* __restrict__ degi,
    int* __restrict__ start, int* __restrict__ cursor, float* __restrict__ dinv)
{
    __shared__ int s[1024];
    int t = threadIdx.x;
    int v[4]; int sum = 0;
    #pragma unroll
    for (int i = 0; i < 4; ++i) {
        int idx = t*4 + i;
        v[i] = (idx < NN) ? degi[idx] : 0;
        sum += v[i];
    }
    s[t] = sum;
    __syncthreads();
    for (int d = 1; d < 1024; d <<= 1) {
        int x = (t >= d) ? s[t-d] : 0;
        __syncthreads();
        s[t] += x;
        __syncthreads();
    }
    int base = s[t] - sum;
    int run = 0;
    #pragma unroll
    for (int i = 0; i < 4; ++i) {
        int idx = t*4 + i;
        if (idx < NN) {
            int st = base + run;
            start[idx] = st;
            cursor[idx] = st;
            dinv[idx] = rsqrtf((float)v[i] + 1.0f);
        }
        run += v[i];
    }
    if (t == 1023) start[NN] = s[1023];
}

__global__ __launch_bounds__(256) void fill_kernel(const int* __restrict__ row,
    const int* __restrict__ col, int* __restrict__ cursor, int* __restrict__ esrc)
{
    int e = blockIdx.x*256 + threadIdx.x;
    if (e < EE) {
        int c = col[e];
        int pos = atomicAdd(&cursor[c], 1);
        esrc[pos] = row[e];
    }
}

__global__ __launch_bounds__(256) void gather_kernel(const float* __restrict__ xw,
    const int* __restrict__ esrc, const int* __restrict__ start,
    const float* __restrict__ dinv, const float* __restrict__ bias,
    float* __restrict__ mout, __hip_bfloat16* __restrict__ mout16, int relu)
{
    int wv = threadIdx.x >> 6, lane = threadIdx.x & 63;
    int n = blockIdx.x*4 + wv;
    if (n >= NN) return;
    float a[8] = {0.f,0.f,0.f,0.f,0.f,0.f,0.f,0.f};
    int s0 = start[n], s1 = start[n+1];
    float dn = dinv[n];
    for (int e = s0; e < s1; ++e) {
        int r = esrc[e];
        float nrm = dinv[r]*dn;
        const float4 v0 = *(const float4*)(xw + (size_t)r*D4 + lane*8);
        const float4 v1 = *(const float4*)(xw + (size_t)r*D4 + lane*8 + 4);
        a[0] += v0.x*nrm; a[1] += v0.y*nrm; a[2] += v0.z*nrm; a[3] += v0.w*nrm;
        a[4] += v1.x*nrm; a[5] += v1.y*nrm; a[6] += v1.z*nrm; a[7] += v1.w*nrm;
    }
    const float4 u0 = *(const float4*)(xw + (size_t)n*D4 + lane*8);
    const float4 u1 = *(const float4*)(xw + (size_t)n*D4 + lane*8 + 4);
    float dd = dn*dn;
    float su[8] = {u0.x,u0.y,u0.z,u0.w,u1.x,u1.y,u1.z,u1.w};
    #pragma unroll
    for (int i = 0; i < 8; ++i) {
        float vv = a[i] + su[i]*dd + bias[lane*8 + i];
        if (relu) vv = fmaxf(vv, 0.0f);
        mout[(size_t)n*D4 + lane*8 + i] = vv;
        if (mout16) mout16[(size_t)n*D4 + lane*8 + i] = __float2bfloat16(vv);
    }
}

// ---------------- head ----------------
__global__ __launch_bounds__(256) void final_kernel(const float* __restrict__ m,
    const float* __restrict__ w, const float* __restrict__ b, float* __restrict__ out)
{
    int wave = threadIdx.x >> 6;
    int lane = threadIdx.x & 63;
    int n = blockIdx.x*4 + wave;
    const float* row = m + (size_t)n*D4 + lane*8;
    float4 v0 = *(const float4*)(row);
    float4 v1 = *(const float4*)(row + 4);
    const float* w0 = w + lane*8;
    const float* w1 = w + D4 + lane*8;
    float4 u0 = *(const float4*)(w0); float4 u1 = *(const float4*)(w0 + 4);
    float4 t0 = *(const float4*)(w1); float4 t1 = *(const float4*)(w1 + 4);
    float a = v0.x*u0.x + v0.y*u0.y + v0.z*u0.z + v0.w*u0.w
            + v1.x*u1.x + v1.y*u1.y + v1.z*u1.z + v1.w*u1.w;
    float bb = v0.x*t0.x + v0.y*t0.y + v0.z*t0.z + v0.w*t0.w
             + v1.x*t1.x + v1.y*t1.y + v1.z*t1.z + v1.w*t1.w;
    #pragma unroll
    for (int s = 32; s; s >>= 1) { a += __shfl_xor(a, s); bb += __shfl_xor(bb, s); }
    if (lane == 0) {
        float l0 = a + b[0], l1 = bb + b[1];
        float mx = fmaxf(l0, l1);
        float e0 = expf(l0 - mx), e1 = expf(l1 - mx);
        float s = e0 + e1;
        out[n]      = e0 / s;
        out[NN + n] = e1 / s;
    }
}

extern "C" void kernel_launch(void* const* d_in, const int* in_sizes, int n_in,
                              void* d_out, int out_size, void* d_ws, size_t ws_size,
                              hipStream_t stream)
{
    const float* feat1 = (const float*)d_in[0];
    const float* feat2 = (const float*)d_in[1];
    const float* feat3 = (const float*)d_in[2];
    const float* feat4 = (const float*)d_in[3];
    const int*   eidx  = (const int*)d_in[4];
    const float* r1w = (const float*)d_in[25]; const float* r1b = (const float*)d_in[26];
    const float* r2w = (const float*)d_in[27]; const float* r2b = (const float*)d_in[28];
    const float* r3w = (const float*)d_in[29]; const float* r3b = (const float*)d_in[30];
    const float* r4w = (const float*)d_in[31]; const float* r4b = (const float*)d_in[32];
    const float* g0w = (const float*)d_in[33]; const float* g0b = (const float*)d_in[34];
    const float* g1w = (const float*)d_in[35]; const float* g1b = (const float*)d_in[36];
    const float* r7w = (const float*)d_in[37]; const float* r7b = (const float*)d_in[38];

    float* ws = (float*)d_ws;
    size_t o = 0;
    auto alloc = [&](size_t nfl) { float* p = ws + o; o += (nfl + 3) & ~(size_t)3; return p; };

    float* hf0 = alloc((size_t)NN*HH);
    float* cf0 = alloc((size_t)2*NN*HH);
    __hip_bfloat16* hb0 = (__hip_bfloat16*)alloc((size_t)3*NN*HH/2);
    size_t zeroFloats = o;                         // hf0, cf0, hb0 zeroed every call
    float* hf1 = alloc((size_t)NN*HH);
    float* cf1 = alloc((size_t)2*NN*HH);
    __hip_bfloat16* hb1 = (__hip_bfloat16*)alloc((size_t)3*NN*HH/2);
    __hip_bfloat16* xg  = (__hip_bfloat16*)alloc((size_t)TG*NN*FF/2);
    __hip_bfloat16* xt  = (__hip_bfloat16*)alloc((size_t)2*TT*NN*FF/2);
    __hip_bfloat16* Wp  = (__hip_bfloat16*)alloc((size_t)3*GCOLS*KCAT/2);
    float* bp   = alloc(3*GCOLS);
    float* mbuf = alloc((size_t)NN*D4);
    float* xwb  = alloc((size_t)NN*D4);
    float* dinv = alloc(NN);
    __hip_bfloat16* mbf16 = (__hip_bfloat16*)alloc((size_t)NN*D4/2);
    __hip_bfloat16* f4b   = (__hip_bfloat16*)alloc((size_t)NN*D4/2);
    __hip_bfloat16* rw123 = (__hip_bfloat16*)alloc((size_t)3*128*HH/2);
    float* rb123 = alloc(3*128);
    __hip_bfloat16* r4w16 = (__hip_bfloat16*)alloc((size_t)128*D4/2);
    __hip_bfloat16* g0w16 = (__hip_bfloat16*)alloc((size_t)D4*D4/2);
    __hip_bfloat16* g1w16 = (__hip_bfloat16*)alloc((size_t)D4*D4/2);
    int* degi   = (int*)alloc(NN);
    int* start  = (int*)alloc(NN + 4);
    int* cursor = (int*)alloc(NN);
    int* esrc   = (int*)alloc(EE);

    float* hfp[2] = {hf0, hf1};
    float* cfp[2] = {cf0, cf1};
    __hip_bfloat16* hbp[2] = {hb0, hb1};

    hipMemsetAsync(hf0, 0, zeroFloats*sizeof(float), stream);
    hipMemsetAsync(degi, 0, NN*sizeof(int), stream);

    prep_w_kernel<<<dim3(3840,1,3),256,0,stream>>>(
        (const float*)d_in[5],(const float*)d_in[6],(const float*)d_in[7],(const float*)d_in[8],
        (const float*)d_in[9],(const float*)d_in[10],(const float*)d_in[11],(const float*)d_in[12],
        (const float*)d_in[13],(const float*)d_in[14],(const float*)d_in[15],(const float*)d_in[16],
        (const float*)d_in[17],(const float*)d_in[18],(const float*)d_in[19],(const float*)d_in[20],
        (const float*)d_in[21],(const float*)d_in[22],(const float*)d_in[23],(const float*)d_in[24],
        Wp, bp);

    tpose_kernel<<<dim3(32000,1,3),256,0,stream>>>(feat1, feat2, feat3, xg, xt);
    f2b_kernel<<<8000,256,0,stream>>>(feat4, f4b, NN*D4);
    f2b_kernel<<<192,256,0,stream>>>(r1w, rw123, 128*HH);
    f2b_kernel<<<192,256,0,stream>>>(r2w, rw123 + 128*HH, 128*HH);
    f2b_kernel<<<192,256,0,stream>>>(r3w, rw123 + 2*128*HH, 128*HH);
    f2b_kernel<<<256,256,0,stream>>>(r4w, r4w16, 128*D4);
    f2b_kernel<<<1024,256,0,stream>>>(g0w, g0w16, D4*D4);
    f2b_kernel<<<1024,256,0,stream>>>(g1w, g1w16, D4*D4);
    hipMemcpyAsync(rb123,       r1b, 128*sizeof(float), hipMemcpyDeviceToDevice, stream);
    hipMemcpyAsync(rb123 + 128, r2b, 128*sizeof(float), hipMemcpyDeviceToDevice, stream);
    hipMemcpyAsync(rb123 + 256, r3b, 128*sizeof(float), hipMemcpyDeviceToDevice, stream);

    count_kernel<<<250,256,0,stream>>>(eidx + EE, degi);
    scan_kernel<<<1,1024,0,stream>>>(degi, start, cursor, dinv);
    fill_kernel<<<250,256,0,stream>>>(eidx, eidx + EE, cursor, esrc);

    // ---- GRU: 32 steps, gate-fused GEMM, h ping-pong ----
    for (int t = 0; t < TG; ++t) {
        int p = t & 1, q = p ^ 1;
        gemm_k<1><<<dim3(GCOLS/BN, 32, 1),256,0,stream>>>(
            xg + (size_t)t*NN*FF, 0, FF, FF,
            hbp[p], 0,
            Wp, 0, KCAT,
            bp, 0, 1,
            hfp[p], 0,
            hfp[q], 0,
            hbp[q], 0,
            HH, NN);
    }
    // ---- Trees: 16 steps, batched z=2, c ping-pong ----
    for (int t = 0; t < TT; ++t) {
        int p = t & 1, q = p ^ 1;
        gemm_k<2><<<dim3(GCOLS/BN, 32, 2),256,0,stream>>>(
            xt + (size_t)t*NN*FF, (size_t)TT*NN*FF, FF, FF,
            hbp[p] + (size_t)NN*HH, (size_t)NN*HH,
            Wp + (size_t)GCOLS*KCAT, (size_t)GCOLS*KCAT, KCAT,
            bp + GCOLS, GCOLS, 1,
            cfp[p], (size_t)NN*HH,
            cfp[q], (size_t)NN*HH,
            hbp[q] + (size_t)NN*HH, (size_t)NN*HH,
            HH, NN);
    }
    // final h's are in hbp[0] slots 0..2 (TG and TT are even)

    // ---- projections r1/r2/r3 batched (z=3), then r4 ----
    gemm_k<0><<<dim3(1,32,3),256,0,stream>>>(
        hbp[0], (size_t)NN*HH, HH, HH, nullptr, 0,
        rw123, (size_t)128*HH, HH,
        rb123, 128, 1,
        nullptr, 0, mbuf, 128,
        mbf16, 128, D4, NN);
    gemm_k<0><<<dim3(1,32,1),256,0,stream>>>(
        f4b, 0, D4, D4, nullptr, 0,
        r4w16, 0, D4,
        r4b, 0, 1,
        nullptr, 0, mbuf + 384, 0,
        mbf16 + 384, 0, D4, NN);

    // ---- GCN layer 0 (relu) ----
    gemm_k<0><<<dim3(4,32,1),256,0,stream>>>(
        mbf16, 0, D4, D4, nullptr, 0,
        g0w16, 0, D4,
        nullptr, 0, 0,
        nullptr, 0, xwb, 0,
        nullptr, 0, D4, NN);
    gather_kernel<<<1000,256,0,stream>>>(xwb, esrc, start, dinv, g0b, mbuf, mbf16, 1);

    // ---- GCN layer 1 ----
    gemm_k<0><<<dim3(4,32,1),256,0,stream>>>(
        mbf16, 0, D4, D4, nullptr, 0,
        g1w16, 0, D4,
        nullptr, 0, 0,
        nullptr, 0, xwb, 0,
        nullptr, 0, D4, NN);
    gather_kernel<<<1000,256,0,stream>>>(xwb, esrc, start, dinv, g1b, mbuf, nullptr, 0);

    final_kernel<<<1000,256,0,stream>>>(mbuf, r7w, r7b, (float*)d_out);
}